// Round 13
// baseline (487.081 us; speedup 1.0000x reference)
//
#include <hip/hip_runtime.h>

// GRU_43387759624777 — Round 13: barrier-free wave-autonomous scan.
//
// R12 post-mortem: occupancy ladder complete & convex (1x16: 871, 2x8: 797,
// 4x4: 926 cyc per 16 rows/CU) — barrier-structure optimum was R11; matrix
// pipe now co-binding at high block counts. This round removes barriers
// entirely: one WAVE owns 4 batch rows and ALL 12 N-tiles (B-frags 24 half8 =
// 96 VGPR). Grid 1024 x 64 thr = 1 wave/SIMD, 24 MFMA/SIMD-step (same pipe
// load as R12) but zero __syncthreads in the scan: h exchange is intra-wave
// via LDS, ordered by the wave's own lgkmcnt (reads of step s precede writes
// of step s in program order; single buffer is safe).
//
// Layout (from verified maps R3..R12): batch row b <-> tile row 4b; lane
// l=16b+c computes gates for (row b, units 16t+c), t=0..3, from D reg 0 of
// each tile. h write: unit 16t+c -> hfrag[t>>1][4b+16*(c>>3)+32*(t&1)][c&7].
// A-frag read: lane l -> hfrag[kt][l][0..7] (rows != 0 mod 4 are garbage but
// only corrupt D regs 1..3, which are discarded — D row m depends only on
// A row m). fp16 1-term MFMA + exp2-domain prescale (absmax 0.0 R9-R12).

#define HID 64
#define SEQ 1024
#define BATCH 4096
#define ROWS 4
#define THREADS 64

typedef __attribute__((ext_vector_type(8))) _Float16 half8;
typedef __attribute__((ext_vector_type(4))) float f32x4;

#define LOG2E 1.44269504088896340736f

__device__ __forceinline__ float rcp_fast(float x) { return __builtin_amdgcn_rcpf(x); }
__device__ __forceinline__ float exp2_fast(float x) { return __builtin_amdgcn_exp2f(x); }

__global__ __launch_bounds__(THREADS, 1) void gru_mfma(
    const float* __restrict__ x,     // [B, T]
    const float* __restrict__ w_ih,  // [192, 1]
    const float* __restrict__ w_hh,  // [192, 64]
    const float* __restrict__ b_ih,  // [192]
    const float* __restrict__ b_hh,  // [192]
    const float* __restrict__ w1,    // [32, 64]
    const float* __restrict__ b1,    // [32]
    const float* __restrict__ w2,    // [16, 32]
    const float* __restrict__ b2,    // [16]
    const float* __restrict__ w3,    // [1, 16]
    const float* __restrict__ b3,    // [1]
    float* __restrict__ out)         // [B, 1]
{
  const int l  = threadIdx.x;        // 0..63 (one wave per block)
  const int b  = l >> 4;             // batch row 0..3 within the wave
  const int c  = l & 15;             // unit-within-tile / B-frag n0
  const int r0 = blockIdx.x * ROWS;  // 1024 blocks x 4 rows

  // ---------------- LDS (~8.3 KB -> 4 blocks/CU trivially) ----------------
  __shared__ __align__(16) _Float16 hfrag[2][64][24];  // [kt][fraglane][.] 6 KB
  __shared__ float hb[ROWS][68];
  __shared__ float ybuf1[ROWS][36];
  __shared__ float ybuf2[ROWS][20];

  // ---------------- B fragments: ALL 12 tiles (fp16, exp2-prescaled) -------
  // bf[gate][t][kt]: lane holds w_hh[gate*64 + 16t + c][kt*32 + b*8 + j]
  half8 bf[3][4][2];
  {
    const float gscale[3] = {-LOG2E, -LOG2E, 2.0f * LOG2E};
    #pragma unroll
    for (int gate = 0; gate < 3; ++gate) {
      #pragma unroll
      for (int t = 0; t < 4; ++t) {
        const int col = gate * 64 + 16 * t + c;
        #pragma unroll
        for (int kt = 0; kt < 2; ++kt) {
          const float* p = w_hh + col * HID + kt * 32 + b * 8;
          half8 v;
          #pragma unroll
          for (int j = 0; j < 8; ++j) v[j] = (_Float16)(p[j] * gscale[gate]);
          bf[gate][t][kt] = v;
        }
      }
    }
  }

  // ---------------- per-lane gate constants for units 16t+c ----------------
  float wir[4], wiz[4], win[4], br[4], bz[4], bni[4], bnh[4], h[4];
  #pragma unroll
  for (int t = 0; t < 4; ++t) {
    const int u = 16 * t + c;
    wir[t] = -LOG2E * w_ih[u];
    wiz[t] = -LOG2E * w_ih[64 + u];
    win[t] = 2.0f * LOG2E * w_ih[128 + u];
    br[t]  = -LOG2E * (b_ih[u] + b_hh[u]);
    bz[t]  = -LOG2E * (b_ih[64 + u] + b_hh[64 + u]);
    bni[t] = 2.0f * LOG2E * b_ih[128 + u];
    bnh[t] = 2.0f * LOG2E * b_hh[128 + u];
    h[t]   = 0.f;
  }

  // write targets: unit 16t+c -> hfrag[t>>1][4b + 16*(c>>3) + 32*(t&1)][c&7]
  const int flo = 4 * b + 16 * (c >> 3);
  const int jj  = c & 7;
  _Float16* wp0 = &hfrag[0][flo][jj];        // t=0
  _Float16* wp1 = &hfrag[0][flo + 32][jj];   // t=1
  _Float16* wp2 = &hfrag[1][flo][jj];        // t=2
  _Float16* wp3 = &hfrag[1][flo + 32][jj];   // t=3

  // zero hfrag (h0 = 0)
  for (int i = l; i < 2 * 64 * 24 / 2; i += THREADS) ((unsigned*)hfrag)[i] = 0u;
  __syncthreads();  // single wave: compiles to a waitcnt; cheap, once

  const float* xrow = x + (size_t)(r0 + b) * SEQ;
  float xc = xrow[0];

  // ---------------- scan: NO barriers ----------------
  #pragma unroll 2
  for (int s = 0; s < SEQ; ++s) {
    // A-fragments (reads precede this step's writes in program order;
    // lgkmcnt ordering within the wave makes the single buffer safe)
    half8 a0 = *(const half8*)&hfrag[0][l][0];
    half8 a1 = *(const half8*)&hfrag[1][l][0];

    // prefetch next step's x (quad-uniform global scalar, L2-resident)
    float xn = xrow[(s < SEQ - 1) ? s + 1 : s];

    f32x4 z4 = {0.f, 0.f, 0.f, 0.f};
    f32x4 aR[4], aZ[4], aN[4];

    // t-group software pipeline: MFMA(t0), MFMA(t1), gates(t0), MFMA(t2),
    // gates(t1), MFMA(t3), gates(t2), gates(t3)
    #define MFMA_T(t)                                                         \
      aR[t] = __builtin_amdgcn_mfma_f32_16x16x32_f16(a0, bf[0][t][0], z4, 0, 0, 0); \
      aZ[t] = __builtin_amdgcn_mfma_f32_16x16x32_f16(a0, bf[1][t][0], z4, 0, 0, 0); \
      aN[t] = __builtin_amdgcn_mfma_f32_16x16x32_f16(a0, bf[2][t][0], z4, 0, 0, 0); \
      aR[t] = __builtin_amdgcn_mfma_f32_16x16x32_f16(a1, bf[0][t][1], aR[t], 0, 0, 0); \
      aZ[t] = __builtin_amdgcn_mfma_f32_16x16x32_f16(a1, bf[1][t][1], aZ[t], 0, 0, 0); \
      aN[t] = __builtin_amdgcn_mfma_f32_16x16x32_f16(a1, bf[2][t][1], aN[t], 0, 0, 0);

    #define GATES_T(t, wp)                                                    \
      {                                                                       \
        float rpp = aR[t][0] + __fmaf_rn(xc, wir[t], br[t]);                  \
        float rr  = rcp_fast(1.0f + exp2_fast(rpp));                          \
        float zpp = aZ[t][0] + __fmaf_rn(xc, wiz[t], bz[t]);                  \
        float zz  = rcp_fast(1.0f + exp2_fast(zpp));                          \
        float npp = __fmaf_rn(rr, aN[t][0] + bnh[t],                          \
                              __fmaf_rn(xc, win[t], bni[t]));                 \
        float nn  = __fmaf_rn(-2.0f, rcp_fast(exp2_fast(npp) + 1.0f), 1.0f);  \
        h[t] = __fmaf_rn(zz, h[t] - nn, nn);                                  \
        *(wp) = (_Float16)h[t];                                               \
      }

    MFMA_T(0)
    MFMA_T(1)
    GATES_T(0, wp0)
    MFMA_T(2)
    GATES_T(1, wp1)
    MFMA_T(3)
    GATES_T(2, wp2)
    GATES_T(3, wp3)

    #undef MFMA_T
    #undef GATES_T
    xc = xn;
  }

  // ---------------- MLP head: 64 -> 32 -> 16 -> 1 (per-wave) ----------------
  __syncthreads();
  #pragma unroll
  for (int t = 0; t < 4; ++t) hb[b][16 * t + c] = h[t];
  __syncthreads();

  #pragma unroll
  for (int rep = 0; rep < 2; ++rep) {            // 4 rows x 32 outs = 128 tasks
    const int o = c + 16 * rep;
    float a = b1[o];
    #pragma unroll
    for (int j4 = 0; j4 < 16; ++j4) {
      f32x4 wv4 = *(const f32x4*)&w1[o * 64 + 4 * j4];
      f32x4 hv  = *(const f32x4*)&hb[b][4 * j4];
      a += wv4[0] * hv[0] + wv4[1] * hv[1] + wv4[2] * hv[2] + wv4[3] * hv[3];
    }
    ybuf1[b][o] = (a > 0.0f) ? a : 0.01f * a;
  }
  __syncthreads();

  {
    const int o = c;                             // 4 rows x 16 outs = 64 tasks
    float a = b2[o];
    #pragma unroll
    for (int j4 = 0; j4 < 8; ++j4) {
      f32x4 wv4 = *(const f32x4*)&w2[o * 32 + 4 * j4];
      f32x4 yv  = *(const f32x4*)&ybuf1[b][4 * j4];
      a += wv4[0] * yv[0] + wv4[1] * yv[1] + wv4[2] * yv[2] + wv4[3] * yv[3];
    }
    ybuf2[b][o] = (a > 0.0f) ? a : 0.01f * a;
  }
  __syncthreads();

  if (l < ROWS) {
    float a = b3[0];
    #pragma unroll
    for (int j = 0; j < 16; ++j) a = __fmaf_rn(w3[j], ybuf2[l][j], a);
    out[r0 + l] = a;
  }
}

extern "C" void kernel_launch(void* const* d_in, const int* in_sizes, int n_in,
                              void* d_out, int out_size, void* d_ws, size_t ws_size,
                              hipStream_t stream) {
  const float* x    = (const float*)d_in[0];
  const float* w_ih = (const float*)d_in[1];
  const float* w_hh = (const float*)d_in[2];
  const float* b_ih = (const float*)d_in[3];
  const float* b_hh = (const float*)d_in[4];
  const float* w1   = (const float*)d_in[5];
  const float* b1   = (const float*)d_in[6];
  const float* w2   = (const float*)d_in[7];
  const float* b2   = (const float*)d_in[8];
  const float* w3   = (const float*)d_in[9];
  const float* b3   = (const float*)d_in[10];
  float* out = (float*)d_out;

  dim3 grid(BATCH / ROWS);  // 1024 single-wave blocks -> 1 wave/SIMD, no barriers
  dim3 block(THREADS);
  hipLaunchKernelGGL(gru_mfma, grid, block, 0, stream,
                     x, w_ih, w_hh, b_ih, b_hh, w1, b1, w2, b2, w3, b3, out);
}

// Round 14
// 354.062 us; speedup vs baseline: 1.3757x; 1.3757x over previous
//
#include <hip/hip_runtime.h>

// GRU_43387759624777 — Round 14: R11 structure (proven optimum) + issue shaves.
//
// Structural map complete (cyc/step per 16 rows/CU): R9 1x16=871, R11 2x8=797
// (best), R12 4x4=926, R13 barrier-free 1wave/SIMD=1088, merge barriers
// +350 each (R8/R10). R11 is the optimum; this round shaves its issue count:
//  - x ds_read_b64 issued BEFORE A-frag reads (data returns under MFMA wait)
//  - packed f32x2 gate preamble + h update (acc regs 0,1 adjacent -> v_pk_*)
//  - hoisted splat constants; RNE cvt kept (RTZ bias not worth 1 op).
//
// Verified invariants (R3..R13): A-frag [m=lane&15][k=(lane>>4)*8+j]; C/D
// col=lane&15, row=(lane>>4)*4+reg; fp16 1-term MFMA + exp2-domain prescale
// (absmax 0.0 R9..R13); interleaved row map b -> A-row 4*(b>>1)+(b&1);
// h(A-row m, unit u) -> hfrag[u>>5][m+16*((u>>3)&3)][u&7]; xT transposed.

#define HID 64
#define SEQ 1024
#define BATCH 4096
#define ROWS 8
#define THREADS 256
#define NTB (SEQ / 64)

typedef __attribute__((ext_vector_type(8))) _Float16 half8;
typedef __attribute__((ext_vector_type(4))) float f32x4;
typedef __attribute__((ext_vector_type(2))) float f32x2;

#define LOG2E 1.44269504088896340736f

__device__ __forceinline__ float rcp_fast(float x) { return __builtin_amdgcn_rcpf(x); }
__device__ __forceinline__ float exp2_fast(float x) { return __builtin_amdgcn_exp2f(x); }
__device__ __forceinline__ f32x2 splat2(float v) { return (f32x2){v, v}; }

__global__ __launch_bounds__(THREADS, 2) void gru_mfma(
    const float* __restrict__ x,     // [B, T]
    const float* __restrict__ w_ih,  // [192, 1]
    const float* __restrict__ w_hh,  // [192, 64]
    const float* __restrict__ b_ih,  // [192]
    const float* __restrict__ b_hh,  // [192]
    const float* __restrict__ w1,    // [32, 64]
    const float* __restrict__ b1,    // [32]
    const float* __restrict__ w2,    // [16, 32]
    const float* __restrict__ b2,    // [16]
    const float* __restrict__ w3,    // [1, 16]
    const float* __restrict__ b3,    // [1]
    float* __restrict__ out)         // [B, 1]
{
  const int L  = threadIdx.x;        // 0..255
  const int l  = L & 63;
  const int wv = L >> 6;             // wave 0..3
  const int r0 = blockIdx.x * ROWS;  // 512 blocks x 8 rows

  // ---------------- LDS (~21 KB -> 2 blocks/CU) ----------------
  __shared__ __align__(16) _Float16 hfrag[2][2][64][24]; // dbuf A-frags, 12 KB
  __shared__ __align__(8) float xT[2][64][10];           // x transposed, 5 KB
  __shared__ float hb[ROWS][68];                         // head h staging
  __shared__ float ybuf1[ROWS][36];
  __shared__ float ybuf2[ROWS][20];

  // ---------------- W fragments (fp16, exp2-prescaled, registers) ----------
  half8 bf[3][2];
  {
    const int n0 = l & 15, q = l >> 4;
    const float gscale[3] = {-LOG2E, -LOG2E, 2.0f * LOG2E};
    #pragma unroll
    for (int gate = 0; gate < 3; ++gate) {
      const int c = gate * 64 + 16 * wv + n0;
      #pragma unroll
      for (int kt = 0; kt < 2; ++kt) {
        const float* p = w_hh + c * HID + kt * 32 + q * 8;
        half8 v;
        #pragma unroll
        for (int j = 0; j < 8; ++j) v[j] = (_Float16)(p[j] * gscale[gate]);
        bf[gate][kt] = v;
      }
    }
  }

  // ---------------- per-lane constants (prescaled, splatted) ----------------
  // Lane owns unit u = 16wv + (l&15), batch rows 2qq, 2qq+1 (A-rows 4qq,4qq+1).
  const int u  = 16 * wv + (l & 15);
  const int qq = l >> 4;
  const f32x2 wir2 = splat2(-LOG2E * w_ih[u]);
  const f32x2 wiz2 = splat2(-LOG2E * w_ih[64 + u]);
  const f32x2 win2 = splat2(2.0f * LOG2E * w_ih[128 + u]);
  const f32x2 br2  = splat2(-LOG2E * (b_ih[u] + b_hh[u]));
  const f32x2 bz2  = splat2(-LOG2E * (b_ih[64 + u] + b_hh[64 + u]));
  const f32x2 bni2 = splat2(2.0f * LOG2E * b_ih[128 + u]);
  const f32x2 bnh2 = splat2(2.0f * LOG2E * b_hh[128 + u]);
  f32x2 h2 = {0.f, 0.f};

  // store target: (A-row m, unit u) -> hfrag[buf][u>>5][m + 16*((u>>3)&3)][u&7]
  const int wkt = u >> 5;
  const int wQ  = (u >> 3) & 3;
  const int wj  = u & 7;
  const int fl0 = 4 * qq + 16 * wQ;

  // zero hfrag (h0 = 0; A-rows {2,3 mod 4} stay zero forever)
  for (int i = L; i < 2 * 2 * 64 * 24 / 2; i += THREADS) ((unsigned*)hfrag)[i] = 0u;

  const float* xblk = x + (size_t)r0 * SEQ;
  const int srow = L >> 4, stq = L & 15;   // staging: 8 rows x 16 quads = 128

  if (L < 128) {  // stage tb=0, transposed
    f32x4 v = *(const f32x4*)(xblk + (size_t)srow * SEQ + stq * 4);
    #pragma unroll
    for (int i = 0; i < 4; ++i) xT[0][stq * 4 + i][srow] = v[i];
  }

  // ---------------- scan: one barrier per step ----------------
  for (int tb = 0; tb < NTB; ++tb) {
    const int par = tb & 1;
    const int tbn = (tb < NTB - 1) ? tb + 1 : tb;
    f32x4 xg = {0.f, 0.f, 0.f, 0.f};
    if (L < 128)  // prefetch next tb's x (64 steps of latency budget)
      xg = *(const f32x4*)(xblk + (size_t)srow * SEQ + tbn * 64 + stq * 4);

    #pragma unroll 2
    for (int s = 0; s < 64; ++s) {
      const int cur = s & 1, nxt = cur ^ 1;
      __syncthreads();  // prev step's hfrag writes (and this tb's xT) visible

      // ---- x first (b64 broadcast), then A-frags: data returns under the
      //      same lgkm wait the MFMAs already need ----
      f32x2 xp = *(const f32x2*)&xT[par][s][2 * qq];
      half8 a0 = *(const half8*)&hfrag[cur][0][l][0];
      half8 a1 = *(const half8*)&hfrag[cur][1][l][0];

      // ---- MFMA: 3 gates x (kt0 -> kt1 chained), 6 total ----
      f32x4 acc0 = {0.f, 0.f, 0.f, 0.f};
      f32x4 acc1 = {0.f, 0.f, 0.f, 0.f};
      f32x4 acc2 = {0.f, 0.f, 0.f, 0.f};
      acc0 = __builtin_amdgcn_mfma_f32_16x16x32_f16(a0, bf[0][0], acc0, 0, 0, 0);
      acc1 = __builtin_amdgcn_mfma_f32_16x16x32_f16(a0, bf[1][0], acc1, 0, 0, 0);
      acc2 = __builtin_amdgcn_mfma_f32_16x16x32_f16(a0, bf[2][0], acc2, 0, 0, 0);
      acc0 = __builtin_amdgcn_mfma_f32_16x16x32_f16(a1, bf[0][1], acc0, 0, 0, 0);
      acc1 = __builtin_amdgcn_mfma_f32_16x16x32_f16(a1, bf[1][1], acc1, 0, 0, 0);
      acc2 = __builtin_amdgcn_mfma_f32_16x16x32_f16(a1, bf[2][1], acc2, 0, 0, 0);

      // ---- packed gate preamble for both rows (v_pk_fma/add) ----
      f32x2 acR = {acc0[0], acc0[1]};
      f32x2 acZ = {acc1[0], acc1[1]};
      f32x2 acN = {acc2[0], acc2[1]};
      f32x2 rpp = acR + xp * wir2 + br2;   // -log2e * rpre
      f32x2 zpp = acZ + xp * wiz2 + bz2;   // -log2e * zpre
      f32x2 npb = xp * win2 + bni2;        // 2log2e * (x*win + bni)
      f32x2 gn  = acN + bnh2;              // 2log2e * (ghn + bnh)

      // ---- transcendentals (scalar, quarter-rate floor) ----
      float Er0 = exp2_fast(rpp[0]), Er1 = exp2_fast(rpp[1]);
      float Ez0 = exp2_fast(zpp[0]), Ez1 = exp2_fast(zpp[1]);
      float rr0 = rcp_fast(1.0f + Er0), rr1 = rcp_fast(1.0f + Er1);
      float zz0 = rcp_fast(1.0f + Ez0), zz1 = rcp_fast(1.0f + Ez1);
      float np0 = __fmaf_rn(rr0, gn[0], npb[0]);
      float np1 = __fmaf_rn(rr1, gn[1], npb[1]);
      float En0 = exp2_fast(np0), En1 = exp2_fast(np1);
      float t0  = rcp_fast(En0 + 1.0f), t1 = rcp_fast(En1 + 1.0f);

      // ---- packed h update: h = n + z*(h - n) ----
      f32x2 nn = {__fmaf_rn(-2.0f, t0, 1.0f), __fmaf_rn(-2.0f, t1, 1.0f)};
      f32x2 zz = {zz0, zz1};
      h2 = nn + zz * (h2 - nn);

      hfrag[nxt][wkt][fl0][wj]     = (_Float16)h2[0];
      hfrag[nxt][wkt][fl0 + 1][wj] = (_Float16)h2[1];
    }

    if (L < 128) {  // stage next tb's x (consumers >= 1 barrier away)
      #pragma unroll
      for (int i = 0; i < 4; ++i) xT[par ^ 1][stq * 4 + i][srow] = xg[i];
    }
  }

  // ---------------- MLP head: 64 -> 32 -> 16 -> 1 ----------------
  __syncthreads();
  hb[2 * qq + 0][u] = h2[0];
  hb[2 * qq + 1][u] = h2[1];
  __syncthreads();

  {
    const int o = L & 31, row = L >> 5;          // 8 rows x 32 outs = 256 tasks
    float a = b1[o];
    #pragma unroll
    for (int j4 = 0; j4 < 16; ++j4) {
      f32x4 wv4 = *(const f32x4*)&w1[o * 64 + 4 * j4];
      f32x4 hv  = *(const f32x4*)&hb[row][4 * j4];
      a += wv4[0] * hv[0] + wv4[1] * hv[1] + wv4[2] * hv[2] + wv4[3] * hv[3];
    }
    ybuf1[row][o] = (a > 0.0f) ? a : 0.01f * a;
  }
  __syncthreads();

  if (L < 128) {
    const int o = L & 15, row = L >> 4;          // 8 rows x 16 outs = 128 tasks
    float a = b2[o];
    #pragma unroll
    for (int j4 = 0; j4 < 8; ++j4) {
      f32x4 wv4 = *(const f32x4*)&w2[o * 32 + 4 * j4];
      f32x4 yv  = *(const f32x4*)&ybuf1[row][4 * j4];
      a += wv4[0] * yv[0] + wv4[1] * yv[1] + wv4[2] * yv[2] + wv4[3] * yv[3];
    }
    ybuf2[row][o] = (a > 0.0f) ? a : 0.01f * a;
  }
  __syncthreads();

  if (L < ROWS) {
    float a = b3[0];
    #pragma unroll
    for (int j = 0; j < 16; ++j) a = __fmaf_rn(w3[j], ybuf2[L][j], a);
    out[r0 + L] = a;
  }
}

extern "C" void kernel_launch(void* const* d_in, const int* in_sizes, int n_in,
                              void* d_out, int out_size, void* d_ws, size_t ws_size,
                              hipStream_t stream) {
  const float* x    = (const float*)d_in[0];
  const float* w_ih = (const float*)d_in[1];
  const float* w_hh = (const float*)d_in[2];
  const float* b_ih = (const float*)d_in[3];
  const float* b_hh = (const float*)d_in[4];
  const float* w1   = (const float*)d_in[5];
  const float* b1   = (const float*)d_in[6];
  const float* w2   = (const float*)d_in[7];
  const float* b2   = (const float*)d_in[8];
  const float* w3   = (const float*)d_in[9];
  const float* b3   = (const float*)d_in[10];
  float* out = (float*)d_out;

  dim3 grid(BATCH / ROWS);  // 512 blocks x 4 waves x 8 rows -> 2 blocks/CU
  dim3 block(THREADS);
  hipLaunchKernelGGL(gru_mfma, grid, block, 0, stream,
                     x, w_ih, w_hh, b_ih, b_hh, w1, b1, w2, b2, w3, b3, out);
}